// Round 9
// baseline (560.886 us; speedup 1.0000x reference)
//
#include <hip/hip_runtime.h>

typedef unsigned short u16;
typedef __bf16 bf16x8 __attribute__((ext_vector_type(8)));
typedef float f32x4 __attribute__((ext_vector_type(4)));
typedef u16 u16x4 __attribute__((ext_vector_type(4)));
typedef u16 u16x8 __attribute__((ext_vector_type(8)));

__device__ __forceinline__ u16 f2bf(float v) {
    unsigned u = __float_as_uint(v);
    unsigned r = (u + 0x7fffu + ((u >> 16) & 1u)) >> 16;
    return (u16)r;
}
__device__ __forceinline__ float bf2f(u16 u) { return __uint_as_float(((unsigned)u) << 16); }

__device__ __forceinline__ void async_cp16(const u16* g, u16* l) {
    __builtin_amdgcn_global_load_lds((const __attribute__((address_space(1))) unsigned int*)g,
                                     (__attribute__((address_space(3))) unsigned int*)l, 16, 0, 0);
}

// bijective XCD-chunked swizzle (m204 variant)
__device__ __forceinline__ int xcd_swz(int local, int n) {
    const int q = n >> 3, r = n & 7;
    const int xcd = local & 7, j = local >> 3;
    const int base = xcd < r ? xcd * (q + 1) : r * (q + 1) + (xcd - r) * q;
    return base + j;
}

// LDS anti-bank-conflict swizzle (T2, rule #21): 16B k-group g within a 64B row r is
// stored at slot g ^ ((r>>1)&3); permutation applied on the GLOBAL source (staging)
// and on the read offset (gload_lds dest must stay linear).
#define LKSWZ(tid) ((((tid) & 3) ^ (((tid) >> 3) & 3)) << 3)
#define ROSWZ(lane) (((lane) & 15) * 32 + ((((lane) >> 4) ^ (((lane) >> 1) & 3)) << 3))

// ---------------- A fp32 -> bf16 convert (pad K 180->192) ----------------
// row-major 65536x180 f32 -> 65536x192 bf16 (cols 180..191 zero). 8 cols/thread.
__global__ __launch_bounds__(256) void conv_a_bf16(
    const float* __restrict__ A, u16* __restrict__ Abf)
{
    const long idx = (long)blockIdx.x * 256 + threadIdx.x;
    const long row = idx / 24;
    const int q = (int)(idx - row * 24);
    u16x8 o = {0, 0, 0, 0, 0, 0, 0, 0};
    if (q < 22) {
        const f32x4 v0 = *(const f32x4*)(A + row * 180L + q * 8);
        const f32x4 v1 = *(const f32x4*)(A + row * 180L + q * 8 + 4);
#pragma unroll
        for (int c = 0; c < 4; c++) { o[c] = f2bf(v0[c]); o[4 + c] = f2bf(v1[c]); }
    } else if (q == 22) {   // cols 176..183: 4 valid + 4 pad
        const f32x4 v0 = *(const f32x4*)(A + row * 180L + 176);
#pragma unroll
        for (int c = 0; c < 4; c++) o[c] = f2bf(v0[c]);
    }
    *(u16x8*)(Abf + row * 192L + q * 8) = o;
}

// ---------------- conv2 GEMM (fp32 out, bias, col guard) ----------------
__global__ __launch_bounds__(256) void gemm_f32(
    const u16* __restrict__ A, const u16* __restrict__ B,
    float* __restrict__ C, const float* __restrict__ bias,
    int K, int ldc, int n_store)
{
    __shared__ char smem[32768];
    u16* As = (u16*)smem;
    u16* Bs = (u16*)(smem + 8192);
    const int tid = threadIdx.x;
    const int lane = tid & 63;
    const int wave = tid >> 6;
    const int wm = wave >> 1, wn = wave & 1;
    const long m0 = (long)blockIdx.y * 128;
    const long n0 = (long)blockIdx.x * 128;

    f32x4 acc[4][4] = {};
    const int lrow = tid >> 2;
    const int lk = LKSWZ(tid);
    const u16* Ag = A + (m0 + lrow) * (long)K + lk;
    const u16* Bg = B + (n0 + lrow) * (long)K + lk;
    u16* Asl = As + tid * 8;
    u16* Bsl = Bs + tid * 8;
    const long K64 = (long)64 * K;
    const int ro = ROSWZ(lane);
    const int nsteps = K >> 5;

    async_cp16(Ag, Asl);
    async_cp16(Ag + K64, Asl + 2048);
    async_cp16(Bg, Bsl);
    async_cp16(Bg + K64, Bsl + 2048);
    __syncthreads();

    int cur = 0;
    for (int s = 0; s < nsteps; s++) {
        if (s + 1 < nsteps) {
            const int kn = (s + 1) << 5;
            u16* An = Asl + ((cur ^ 1) << 13);
            u16* Bn = Bsl + ((cur ^ 1) << 13);
            async_cp16(Ag + kn, An);
            async_cp16(Ag + kn + K64, An + 2048);
            async_cp16(Bg + kn, Bn);
            async_cp16(Bg + kn + K64, Bn + 2048);
        }
        bf16x8 af[4], bg[4];
        const u16* Asc = As + (cur << 13);
        const u16* Bsc = Bs + (cur << 13);
#pragma unroll
        for (int i = 0; i < 4; i++) af[i] = *(const bf16x8*)(Asc + (wm * 64 + i * 16) * 32 + ro);
#pragma unroll
        for (int j = 0; j < 4; j++) bg[j] = *(const bf16x8*)(Bsc + (wn * 64 + j * 16) * 32 + ro);
#pragma unroll
        for (int i = 0; i < 4; i++)
#pragma unroll
            for (int j = 0; j < 4; j++)
                acc[i][j] = __builtin_amdgcn_mfma_f32_16x16x32_bf16(af[i], bg[j], acc[i][j], 0, 0, 0);
        __syncthreads();
        cur ^= 1;
    }

    float bv[4];
#pragma unroll
    for (int j = 0; j < 4; j++) bv[j] = bias[n0 + wn * 64 + j * 16 + (lane & 15)];

    float* Cs = (float*)smem;
    for (int c = 0; c < 4; c++) {
        __syncthreads();
        if (wm == (c >> 1)) {
#pragma unroll
            for (int ii = 0; ii < 2; ii++) {
                const int i = (c & 1) * 2 + ii;
#pragma unroll
                for (int j = 0; j < 4; j++)
#pragma unroll
                    for (int r = 0; r < 4; r++) {
                        const int lr = ii * 16 + ((lane >> 4) << 2) + r;
                        Cs[lr * 128 + wn * 64 + j * 16 + (lane & 15)] = acc[i][j][r] + bv[j];
                    }
            }
        }
        __syncthreads();
        const int lr = tid >> 3;
        const int cg = (tid & 7) * 16;
        const long rowg = m0 + c * 32 + lr;
#pragma unroll
        for (int e = 0; e < 4; e++) {
            const int colg = cg + e * 4;
            if ((int)n0 + colg < n_store)
                *(f32x4*)(C + rowg * (long)ldc + n0 + colg) = *(const f32x4*)(Cs + lr * 128 + colg);
        }
    }
}

// ---------------- conv1: x = Abf(65536x192 bf16) @ W1t^T + b1, dbuf gload_lds, fused BN stats ----------------
__global__ __launch_bounds__(256) void conv1_gemm(
    const u16* __restrict__ A, const u16* __restrict__ B,
    u16* __restrict__ C, const float* __restrict__ bias, float* __restrict__ accum)
{
    __shared__ char smem[32768];
    u16* As = (u16*)smem;
    u16* Bs = (u16*)(smem + 8192);
    const int tid = threadIdx.x;
    const int lane = tid & 63;
    const int wave = tid >> 6;
    const int wm = wave >> 1, wn = wave & 1;
    const long m0 = (long)blockIdx.y * 128;
    const long n0 = (long)blockIdx.x * 128;

    f32x4 acc[4][4] = {};
    const int lrow = tid >> 2;
    const int lk = LKSWZ(tid);
    const u16* Ag = A + (m0 + lrow) * 192L + lk;
    const u16* Bg = B + (n0 + lrow) * 192L + lk;
    u16* Asl = As + tid * 8;
    u16* Bsl = Bs + tid * 8;
    const long K64 = 64L * 192;
    const int ro = ROSWZ(lane);
    const int nsteps = 6;

    async_cp16(Ag, Asl);
    async_cp16(Ag + K64, Asl + 2048);
    async_cp16(Bg, Bsl);
    async_cp16(Bg + K64, Bsl + 2048);
    __syncthreads();

    int cur = 0;
    for (int s = 0; s < nsteps; s++) {
        if (s + 1 < nsteps) {
            const int kn = (s + 1) << 5;
            u16* An = Asl + ((cur ^ 1) << 13);
            u16* Bn = Bsl + ((cur ^ 1) << 13);
            async_cp16(Ag + kn, An);
            async_cp16(Ag + kn + K64, An + 2048);
            async_cp16(Bg + kn, Bn);
            async_cp16(Bg + kn + K64, Bn + 2048);
        }
        bf16x8 af[4], bg[4];
        const u16* Asc = As + (cur << 13);
        const u16* Bsc = Bs + (cur << 13);
#pragma unroll
        for (int i = 0; i < 4; i++) af[i] = *(const bf16x8*)(Asc + (wm * 64 + i * 16) * 32 + ro);
#pragma unroll
        for (int j = 0; j < 4; j++) bg[j] = *(const bf16x8*)(Bsc + (wn * 64 + j * 16) * 32 + ro);
#pragma unroll
        for (int i = 0; i < 4; i++)
#pragma unroll
            for (int j = 0; j < 4; j++)
                acc[i][j] = __builtin_amdgcn_mfma_f32_16x16x32_bf16(af[i], bg[j], acc[i][j], 0, 0, 0);
        __syncthreads();
        cur ^= 1;
    }

    float bv[4];
#pragma unroll
    for (int j = 0; j < 4; j++) bv[j] = bias[n0 + wn * 64 + j * 16 + (lane & 15)];

    // fused BN stats: sum ROUNDED bf16 values (matches what consumers read).
    {
        float bs[4], bs2[4];
#pragma unroll
        for (int j = 0; j < 4; j++) {
            float s = 0.0f, s2 = 0.0f;
#pragma unroll
            for (int i = 0; i < 4; i++)
#pragma unroll
                for (int r = 0; r < 4; r++) {
                    const float v = bf2f(f2bf(acc[i][j][r] + bv[j]));
                    s += v; s2 += v * v;
                }
            s += __shfl_xor(s, 16, 64);  s += __shfl_xor(s, 32, 64);
            s2 += __shfl_xor(s2, 16, 64); s2 += __shfl_xor(s2, 32, 64);
            bs[j] = s; bs2[j] = s2;
        }
        if (lane < 16) {
#pragma unroll
            for (int j = 0; j < 4; j++) {
                const int ch = (int)n0 + wn * 64 + j * 16 + lane;
                atomicAdd(&accum[ch], bs[j]);
                atomicAdd(&accum[384 + ch], bs2[j]);
            }
        }
    }

    u16* Cs = (u16*)smem;
    for (int c = 0; c < 2; c++) {
        __syncthreads();
        if (wm == c) {
#pragma unroll
            for (int i = 0; i < 4; i++)
#pragma unroll
                for (int j = 0; j < 4; j++)
#pragma unroll
                    for (int r = 0; r < 4; r++) {
                        const int lr = i * 16 + ((lane >> 4) << 2) + r;
                        Cs[lr * 128 + wn * 64 + j * 16 + (lane & 15)] = f2bf(acc[i][j][r] + bv[j]);
                    }
        }
        __syncthreads();
        const int lr = tid >> 2;
        const int cg = (tid & 3) * 32;
        const long rowg = m0 + c * 64 + lr;
#pragma unroll
        for (int e = 0; e < 4; e++) {
            const int colg = cg + e * 8;
            *(u16x8*)(C + rowg * 384L + n0 + colg) = *(const u16x8*)(Cs + lr * 128 + colg);
        }
    }
}

// ---------------- grouped qq^T: SYMMETRIC (upper-tri) + split-K + XCD swizzle + dbuf ----------------
// blocks: [0,528) g0 tri(32) z=1 | [528,816) g1 tri(8) z=8 | [816,996) g2 tri(2) z=60
__global__ __launch_bounds__(256) void qq_all(
    const u16* __restrict__ q0, const u16* __restrict__ q1, const u16* __restrict__ q2,
    float* __restrict__ S0, float* __restrict__ pG1, float* __restrict__ pG2)
{
    __shared__ char smem[32768];
    u16* As = (u16*)smem;
    u16* Bs = (u16*)(smem + 8192);
    const int bid = blockIdx.x;
    int seg, local;
    if (bid < 528) { seg = 0; local = xcd_swz(bid, 528); }
    else if (bid < 816) { seg = 1; local = xcd_swz(bid - 528, 288); }
    else { seg = 2; local = xcd_swz(bid - 816, 180); }
    const int tX = seg == 0 ? 32 : (seg == 1 ? 8 : 2);
    const int TT = (tX * (tX + 1)) >> 1;
    const int K = seg == 0 ? 1024 : (seg == 1 ? 3840 : 15360);
    const int Ksplit = seg == 0 ? 1024 : (seg == 1 ? 480 : 256);
    const int N = seg == 0 ? 4096 : (seg == 1 ? 1024 : 256);
    const u16* A = seg == 0 ? q0 : (seg == 1 ? q1 : q2);
    float* outP = seg == 0 ? S0 : (seg == 1 ? pG1 : pG2);
    const int z = local / TT;
    int rem = local - z * TT;
    int by = 0, rowlen = tX;
    while (rem >= rowlen) { rem -= rowlen; by++; rowlen--; }
    const int bx = by + rem;

    const int tid = threadIdx.x;
    const int lane = tid & 63;
    const int wave = tid >> 6;
    const int wm = wave >> 1, wn = wave & 1;
    const long m0 = (long)by * 128;
    const long n0 = (long)bx * 128;
    const int kbeg = z * Ksplit;

    f32x4 acc[4][4] = {};
    const int lrow = tid >> 2;
    const int lk = LKSWZ(tid);
    const u16* Ag = A + (m0 + lrow) * (long)K + lk;
    const u16* Bg = A + (n0 + lrow) * (long)K + lk;
    u16* Asl = As + tid * 8;
    u16* Bsl = Bs + tid * 8;
    const long K64 = (long)64 * K;
    const int ro = ROSWZ(lane);
    const int nsteps = Ksplit >> 5;

    async_cp16(Ag + kbeg, Asl);
    async_cp16(Ag + kbeg + K64, Asl + 2048);
    async_cp16(Bg + kbeg, Bsl);
    async_cp16(Bg + kbeg + K64, Bsl + 2048);
    __syncthreads();

    int cur = 0;
    for (int s = 0; s < nsteps; s++) {
        if (s + 1 < nsteps) {
            const int kn = kbeg + ((s + 1) << 5);
            u16* An = Asl + ((cur ^ 1) << 13);
            u16* Bn = Bsl + ((cur ^ 1) << 13);
            async_cp16(Ag + kn, An);
            async_cp16(Ag + kn + K64, An + 2048);
            async_cp16(Bg + kn, Bn);
            async_cp16(Bg + kn + K64, Bn + 2048);
        }
        bf16x8 af[4], bg[4];
        const u16* Asc = As + (cur << 13);
        const u16* Bsc = Bs + (cur << 13);
#pragma unroll
        for (int i = 0; i < 4; i++) af[i] = *(const bf16x8*)(Asc + (wm * 64 + i * 16) * 32 + ro);
#pragma unroll
        for (int j = 0; j < 4; j++) bg[j] = *(const bf16x8*)(Bsc + (wn * 64 + j * 16) * 32 + ro);
#pragma unroll
        for (int i = 0; i < 4; i++)
#pragma unroll
            for (int j = 0; j < 4; j++)
                acc[i][j] = __builtin_amdgcn_mfma_f32_16x16x32_bf16(af[i], bg[j], acc[i][j], 0, 0, 0);
        __syncthreads();
        cur ^= 1;
    }

    float* Pz = outP + (long)z * N * N;

    // mirror write (transposed tile) straight from accumulators
    if (bx != by) {
        const int r0 = (int)n0 + wn * 64 + (lane & 15);
        const int c0 = (int)m0 + wm * 64 + ((lane >> 4) << 2);
#pragma unroll
        for (int j = 0; j < 4; j++) {
            float* rp = Pz + (long)(r0 + j * 16) * N + c0;
#pragma unroll
            for (int i = 0; i < 4; i++)
                *(f32x4*)(rp + i * 16) = acc[i][j];
        }
    }

    float* Cs = (float*)smem;
    for (int c = 0; c < 4; c++) {
        __syncthreads();
        if (wm == (c >> 1)) {
#pragma unroll
            for (int ii = 0; ii < 2; ii++) {
                const int i = (c & 1) * 2 + ii;
#pragma unroll
                for (int j = 0; j < 4; j++)
#pragma unroll
                    for (int r = 0; r < 4; r++) {
                        const int lr = ii * 16 + ((lane >> 4) << 2) + r;
                        Cs[lr * 128 + wn * 64 + j * 16 + (lane & 15)] = acc[i][j][r];
                    }
            }
        }
        __syncthreads();
        const int lr = tid >> 3;
        const int cg = (tid & 7) * 16;
        const long rowg = m0 + c * 32 + lr;
#pragma unroll
        for (int e = 0; e < 4; e++) {
            const int colg = cg + e * 4;
            *(f32x4*)(Pz + rowg * (long)N + n0 + colg) = *(const f32x4*)(Cs + lr * 128 + colg);
        }
    }
}

// ---------------- grouped PV (XCD swizzle + dbuf) + fused g0 split-K winner-reduce ----------------
// blocks: [0,512) g0 8x32 split-K z=2 | [512,752) g1 30x8 | [752,992) g2 120x2
// g0: both z write fp32 partials; the SECOND finisher of each tile (atomic counter)
// re-reads both partials and does the windowed bf16 scatter inline (replaces
// reduce_scatter_g0). threadfence+atomic = device-scope release/acquire (G12/G16).
__global__ __launch_bounds__(256, 4) void pv_all(
    const u16* __restrict__ a0, const u16* __restrict__ a1, const u16* __restrict__ a2,
    const u16* __restrict__ vt0, const u16* __restrict__ vt1, const u16* __restrict__ vt2,
    u16* __restrict__ Ysp, float* __restrict__ pP0, float* __restrict__ pP1,
    int* __restrict__ cnt)
{
    __shared__ char smem[32768];
    __shared__ int role;
    u16* As = (u16*)smem;
    u16* Bs = (u16*)(smem + 8192);
    const int bid = blockIdx.x;
    int seg, local, z = 0;
    if (bid < 512) { seg = 0; const int l = xcd_swz(bid, 512); z = l >> 8; local = l & 255; }
    else if (bid < 752) { seg = 1; local = xcd_swz(bid - 512, 240); }
    else { seg = 2; local = xcd_swz(bid - 752, 240); }
    const int tX = seg == 0 ? 8 : (seg == 1 ? 30 : 120);
    const int K = seg == 0 ? 4096 : (seg == 1 ? 1024 : 256);
    const int Ksplit = seg == 0 ? 2048 : K;
    const int D = seg == 0 ? 960 : (seg == 1 ? 3840 : 15360);
    const int l2ws = 2 + seg;
    const int l2wc = 5 - seg;
    const u16* A = seg == 0 ? a0 : (seg == 1 ? a1 : a2);
    const u16* B = seg == 0 ? vt0 : (seg == 1 ? vt1 : vt2);
    const int bx = local % tX;
    const int by = local / tX;

    const int tid = threadIdx.x;
    const int lane = tid & 63;
    const int wave = tid >> 6;
    const int wm = wave >> 1, wn = wave & 1;
    const long m0 = (long)by * 128;     // n (window) rows
    const long n0 = (long)bx * 128;     // d cols
    const int kbeg = z * Ksplit;

    f32x4 acc[4][4] = {};
    const int lrow = tid >> 2;
    const int lk = LKSWZ(tid);
    const u16* Ag = A + (m0 + lrow) * (long)K + lk;
    const u16* Bg = B + (n0 + lrow) * (long)K + lk;
    u16* Asl = As + tid * 8;
    u16* Bsl = Bs + tid * 8;
    const long K64 = (long)64 * K;
    const int ro = ROSWZ(lane);
    const int nsteps = Ksplit >> 5;

    async_cp16(Ag + kbeg, Asl);
    async_cp16(Ag + kbeg + K64, Asl + 2048);
    async_cp16(Bg + kbeg, Bsl);
    async_cp16(Bg + kbeg + K64, Bsl + 2048);
    __syncthreads();

    int cur = 0;
    for (int s = 0; s < nsteps; s++) {
        if (s + 1 < nsteps) {
            const int kn = kbeg + ((s + 1) << 5);
            u16* An = Asl + ((cur ^ 1) << 13);
            u16* Bn = Bsl + ((cur ^ 1) << 13);
            async_cp16(Ag + kn, An);
            async_cp16(Ag + kn + K64, An + 2048);
            async_cp16(Bg + kn, Bn);
            async_cp16(Bg + kn + K64, Bn + 2048);
        }
        bf16x8 af[4], bg[4];
        const u16* Asc = As + (cur << 13);
        const u16* Bsc = Bs + (cur << 13);
#pragma unroll
        for (int i = 0; i < 4; i++) af[i] = *(const bf16x8*)(Asc + (wm * 64 + i * 16) * 32 + ro);
#pragma unroll
        for (int j = 0; j < 4; j++) bg[j] = *(const bf16x8*)(Bsc + (wn * 64 + j * 16) * 32 + ro);
#pragma unroll
        for (int i = 0; i < 4; i++)
#pragma unroll
            for (int j = 0; j < 4; j++)
                acc[i][j] = __builtin_amdgcn_mfma_f32_16x16x32_bf16(af[i], bg[j], acc[i][j], 0, 0, 0);
        __syncthreads();
        cur ^= 1;
    }

    if (seg == 0) {
        // write own fp32 partial (4096 x 1024 row-major), coalesced via LDS restage
        float* Pz = (z == 0) ? pP0 : pP1;
        float* Po = (z == 0) ? pP1 : pP0;
        float* Cs = (float*)smem;
        for (int c = 0; c < 4; c++) {
            __syncthreads();
            if (wm == (c >> 1)) {
#pragma unroll
                for (int ii = 0; ii < 2; ii++) {
                    const int i = (c & 1) * 2 + ii;
#pragma unroll
                    for (int j = 0; j < 4; j++)
#pragma unroll
                        for (int r = 0; r < 4; r++) {
                            const int lr = ii * 16 + ((lane >> 4) << 2) + r;
                            Cs[lr * 128 + wn * 64 + j * 16 + (lane & 15)] = acc[i][j][r];
                        }
                }
            }
            __syncthreads();
            const int lr = tid >> 3;
            const int cg = (tid & 7) * 16;
            const long rowg = m0 + c * 32 + lr;
#pragma unroll
            for (int e = 0; e < 4; e++) {
                const int colg = cg + e * 4;
                *(f32x4*)(Pz + rowg * 1024L + n0 + colg) = *(const f32x4*)(Cs + lr * 128 + colg);
            }
        }
        // winner-reduce handshake: release own writes, count arrivals on this tile.
        __threadfence();
        __syncthreads();
        if (tid == 0) role = atomicAdd(&cnt[by * 8 + bx], 1);
        __syncthreads();
        if (role == 0) return;     // first finisher: partial stored, done
        __threadfence();           // acquire: make loser's partial visible
        const int lr = tid >> 3;
        const int cg = (tid & 7) * 16;
        for (int c = 0; c < 4; c++) {
            const long rowg = m0 + c * 32 + lr;
            const int n = (int)rowg;
            const int wi = n & 31;
            const int hi = (n >> 5) & 31;
            const int b = n >> 10;
#pragma unroll
            for (int e = 0; e < 4; e++) {
                const int d = (int)n0 + cg + e * 4;
                if (d < 960) {
                    const long idx = rowg * 1024L + d;
                    f32x4 s = *(const f32x4*)(Pz + idx) + *(const f32x4*)(Po + idx);
                    const int cc = d % 60;
                    const int pp = d / 60;
                    const int dh = pp >> 2;
                    const int dw = pp & 3;
                    const int row = ((hi << 2) + dh + 2) & 127;
                    const int col = ((wi << 2) + dw + 2) & 127;
                    u16x4 o;
#pragma unroll
                    for (int k = 0; k < 4; k++) o[k] = f2bf(s[k]);
                    *(u16x4*)(Ysp + ((long)((b << 7) + row) * 128 + col) * 192 + cc) = o;
                }
            }
        }
        return;
    }

    // g1/g2: bf16 scatter epilogue
    u16* Cs = (u16*)smem;
    const int wcm = (1 << l2wc) - 1;
    const int wsm = (1 << l2ws) - 1;
    const int sh = 1 << (l2ws - 1);
    for (int c = 0; c < 2; c++) {
        __syncthreads();
        if (wm == c) {
#pragma unroll
            for (int i = 0; i < 4; i++)
#pragma unroll
                for (int j = 0; j < 4; j++)
#pragma unroll
                    for (int r = 0; r < 4; r++) {
                        const int lr = i * 16 + ((lane >> 4) << 2) + r;
                        Cs[lr * 128 + wn * 64 + j * 16 + (lane & 15)] = f2bf(acc[i][j][r]);
                    }
        }
        __syncthreads();
        const int lr = tid >> 2;
        const int cgbase = (tid & 3) * 32;
        const int n = (int)m0 + c * 64 + lr;
        const int wi = n & wcm;
        const int hi = (n >> l2wc) & wcm;
        const int bb = n >> (2 * l2wc);
        const int rowb = (hi << l2ws) + sh;
        const int colb = (wi << l2ws) + sh;
        const long bbase = (long)bb * 128 * 128 * 192 + 60 * seg;
#pragma unroll
        for (int e = 0; e < 8; e++) {
            const int colg = cgbase + e * 4;
            const int d = (int)n0 + colg;
            if (d < D) {
                const int cc = d % 60;
                const int pp = d / 60;
                const int dh = pp >> l2ws;
                const int dw = pp & wsm;
                const int row = (rowb + dh) & 127;
                const int col = (colb + dw) & 127;
                *(u16x4*)(Ysp + bbase + ((long)row * 128 + col) * 192 + cc) =
                    *(const u16x4*)(Cs + lr * 128 + colg);
            }
        }
    }
}

// ---------------- prep: W1t, W2t, padded biases, accum+counters zero ----------------
__global__ __launch_bounds__(192) void prep_all(
    const float* __restrict__ W1, const float* __restrict__ W2,
    const float* __restrict__ b1, const float* __restrict__ b2,
    u16* __restrict__ W1t, u16* __restrict__ W2t,
    float* __restrict__ b1p, float* __restrict__ b2p, float* __restrict__ accum)
{
    const int bid = blockIdx.x;
    const int t = threadIdx.x;
    if (bid < 384) {
        W1t[bid * 192 + t] = (bid < 360 && t < 180) ? f2bf(W1[t * 360 + bid]) : (u16)0;
    } else if (bid < 640) {
        const int n = bid - 384;
        W2t[n * 192 + t] = (n < 180 && t < 180) ? f2bf(W2[t * 180 + n]) : (u16)0;
    } else {
#pragma unroll
        for (int j = 0; j < 8; j++) {
            const int i = t + 192 * j;
            if (i < 384) b1p[i] = (i < 360) ? b1[i] : 0.0f;
            else if (i < 640) { const int k = i - 384; b2p[k] = (k < 180) ? b2[k] : 0.0f; }
            if (i < 1536) accum[i] = 0.0f;   // [0,768) BN sums, [1024,1280) split-K counters
        }
    }
}

// ---------------- grouped gather + inline BN + transpose ----------------
// blocks: [0,1024) g0 16x64 | [1024,1984) g1 60x16 | [1984,2944) g2 240x4
__global__ __launch_bounds__(256) void gather_all(
    const u16* __restrict__ x, const float* __restrict__ accum,
    const float* __restrict__ bns, const float* __restrict__ bnb,
    u16* __restrict__ q0, u16* __restrict__ q1, u16* __restrict__ q2,
    u16* __restrict__ vt0, u16* __restrict__ vt1, u16* __restrict__ vt2)
{
    __shared__ u16 t[64][65];
    const int bid = blockIdx.x;
    int seg, local;
    if (bid < 1024) { seg = 0; local = bid; }
    else if (bid < 1984) { seg = 1; local = bid - 1024; }
    else { seg = 2; local = bid - 1984; }
    const int tX = seg == 0 ? 16 : (seg == 1 ? 60 : 240);
    const int N = seg == 0 ? 4096 : (seg == 1 ? 1024 : 256);
    const int D = seg == 0 ? 960 : (seg == 1 ? 3840 : 15360);
    const int Dp = seg == 0 ? 1024 : (seg == 1 ? 3840 : 15360);
    const int l2ws = 2 + seg;
    const int l2wc = 5 - seg;
    u16* q = seg == 0 ? q0 : (seg == 1 ? q1 : q2);
    u16* vt = seg == 0 ? vt0 : (seg == 1 ? vt1 : vt2);
    const int bx = local % tX;
    const int by = local / tX;

    const int d0 = bx * 64;
    const int n0 = by * 64;
    const int tc = threadIdx.x & 63;
    const int tr = threadIdx.x >> 6;

    const int d = d0 + tc;
    const int sh = 1 << (l2ws - 1);
    const int cc = d % 60;
    const int pp = d / 60;
    const int dh = pp >> l2ws;
    const int dw = pp & ((1 << l2ws) - 1);
    const int wcm = (1 << l2wc) - 1;
    const int ch = 120 * seg + cc;
    // inline bn_finalize
    const float m_q = accum[ch] * (1.0f / 65536.0f);
    const float v_q = accum[384 + ch] * (1.0f / 65536.0f) - m_q * m_q;
    const float seq = bns[ch] * rsqrtf(v_q + 1e-5f);
    const float beq = bnb[ch] - m_q * seq;
    const float m_v = accum[ch + 60] * (1.0f / 65536.0f);
    const float v_v = accum[384 + ch + 60] * (1.0f / 65536.0f) - m_v * m_v;
    const float sev = bns[ch + 60] * rsqrtf(v_v + 1e-5f);
    const float bev = bnb[ch + 60] - m_v * sev;
    const bool valid = d < D;

#pragma unroll 4
    for (int i = 0; i < 16; i++) {
        const int n = n0 + i * 4 + tr;
        const int wi = n & wcm;
        const int hi = (n >> l2wc) & wcm;
        const int b = n >> (2 * l2wc);
        const int row = ((hi << l2ws) + dh + sh) & 127;
        const int col = ((wi << l2ws) + dw + sh) & 127;
        const long src = ((long)((b << 7) + row) * 128 + col) * 384 + ch;
        const float xq = bf2f(x[src]);
        const float xv = bf2f(x[src + 60]);
        q[(long)n * Dp + d] = valid ? f2bf(seq * xq + beq) : (u16)0;
        t[tc][i * 4 + tr] = f2bf(sev * xv + bev);
    }
    __syncthreads();
#pragma unroll 4
    for (int i = 0; i < 16; i++) {
        const int dd = i * 4 + tr;
        vt[(long)(d0 + dd) * N + n0 + tc] = t[dd][tc];
    }
}

// ---------------- grouped softmax (fused split-K reduce) + zero_pad merged ----------------
template <int VPT>
__device__ __forceinline__ void softmax_body(
    const float* __restrict__ P, int nsplit, long MN, int rowi,
    float* __restrict__ S, u16* __restrict__ Sb)
{
    const int N = VPT * 256;
    const long base = (long)rowi * N;
    float v[VPT];
    float mx = -3.0e38f;
#pragma unroll
    for (int i = 0; i < VPT; i++) {
        const long idx = base + i * 256 + threadIdx.x;
        float val = P[idx];
        for (int z = 1; z < nsplit; z++) val += P[(long)z * MN + idx];
        v[i] = val; mx = fmaxf(mx, val);
    }
#pragma unroll
    for (int o = 32; o > 0; o >>= 1) mx = fmaxf(mx, __shfl_down(mx, o, 64));
    __shared__ float redm[4];
    if ((threadIdx.x & 63) == 0) redm[threadIdx.x >> 6] = mx;
    __syncthreads();
    mx = fmaxf(fmaxf(redm[0], redm[1]), fmaxf(redm[2], redm[3]));
    float s = 0.0f;
#pragma unroll
    for (int i = 0; i < VPT; i++) { v[i] = __expf(v[i] - mx); s += v[i]; }
#pragma unroll
    for (int o = 32; o > 0; o >>= 1) s += __shfl_down(s, o, 64);
    __shared__ float reds[4];
    if ((threadIdx.x & 63) == 0) reds[threadIdx.x >> 6] = s;
    __syncthreads();
    s = reds[0] + reds[1] + reds[2] + reds[3];
    const float inv = 1.0f / s;
#pragma unroll
    for (int i = 0; i < VPT; i++) {
        const float r = v[i] * inv;
        const long idx = base + i * 256 + threadIdx.x;
        S[idx] = r;
        Sb[idx] = f2bf(r);
    }
}

__global__ __launch_bounds__(256) void softmax_all(
    float* __restrict__ S0, const float* __restrict__ pG1, const float* __restrict__ pG2,
    float* __restrict__ out1, float* __restrict__ out2,
    u16* __restrict__ ab0, u16* __restrict__ ab1, u16* __restrict__ ab2,
    u16* __restrict__ Ysp)
{
    const int r = blockIdx.x;
    if (r >= 5376) {   // zero Ysp pad cols 180..191 (merged zero_pad)
        const long rr = (long)(r - 5376) * 256 + threadIdx.x;
        u16* p = Ysp + rr * 192 + 180;
        const u16x4 zz = {0, 0, 0, 0};
        *(u16x4*)(p) = zz;
        *(u16x4*)(p + 4) = zz;
        *(u16x4*)(p + 8) = zz;
        return;
    }
    if (r < 4096)      softmax_body<16>(S0, 1, 16777216L, r, S0, ab0);
    else if (r < 5120) softmax_body<4>(pG1, 8, 1048576L, r - 4096, out1, ab1);
    else               softmax_body<1>(pG2, 60, 65536L, r - 5120, out2, ab2);
}

extern "C" void kernel_launch(void* const* d_in, const int* in_sizes, int n_in,
                              void* d_out, int out_size, void* d_ws, size_t ws_size,
                              hipStream_t stream)
{
    const float* in_x = (const float*)d_in[0];
    const float* w1  = (const float*)d_in[1];
    const float* b1  = (const float*)d_in[2];
    const float* bns = (const float*)d_in[3];
    const float* bnb = (const float*)d_in[4];
    const float* w2  = (const float*)d_in[5];
    const float* b2  = (const float*)d_in[6];
    float* out = (float*)d_out;

    char* w = (char*)d_ws;
    // region0 (33.55 MB): atnb0 (g0 bf16 atn, softmax_all -> pv_all)
    u16* atnb0 = (u16*)w;
    size_t off = 33554432;
    // x region (50.33 MB): x (conv1 out, dead after gather_all);
    //   then qq partials pG1 (33.55 @ +0), pG2 (15.73 @ +33.55) [dead after softmax_all];
    //   then Ysp (25.17 @ +0) and pP1 (g0 PV partial z1, 16.78 @ +25.17).
    u16* x = (u16*)(w + off);
    float* pG1 = (float*)(w + off);
    float* pG2 = (float*)(w + off + 33554432);
    u16* Ysp = (u16*)(w + off);
    float* pP1 = (float*)(w + off + 25165824);
    off += 50331648;
    u16* W1t = (u16*)(w + off);  off += 147456;
    u16* W2t = (u16*)(w + off);  off += 98304;
    float* b1p = (float*)(w + off);   off += 4096;
    float* b2p = (float*)(w + off);   off += 4096;
    float* accum = (float*)(w + off); off += 8192;
    u16* q0 = (u16*)(w + off);  off += 8388608;
    u16* q1 = (u16*)(w + off);  off += 7864320;
    u16* q2 = (u16*)(w + off);  off += 7864320;
    u16* vt0 = (u16*)(w + off); off += 8388608;
    u16* vt1 = (u16*)(w + off); off += 7864320;
    u16* vt2 = (u16*)(w + off); off += 7864320;
    u16* atnb1 = (u16*)(w + off); off += 2097152;
    u16* atnb2 = (u16*)(w + off); off += 131072;
    // pP0 (g0 PV partial z0, 16.78 MB) overlays dead q0/q1/q2 (24.1 MB)
    float* pP0 = (float*)q0;
    // Abf (65536x192 bf16, 25.17 MB) overlays q0..q2+head of vt0; dead before gather_all
    u16* Abf = q0;
    // split-K tile counters: 256 ints inside accum page at float-offset 1024
    int* cnt = (int*)(accum + 1024);

    float* S0 = out + 11796480L;   // atn g0 (4096^2)
    float* S1 = out + 28573696L;   // atn g1 (1024^2)
    float* S2 = out + 29622272L;   // atn g2 (256^2)

    prep_all<<<641, 192, 0, stream>>>(w1, w2, b1, b2, W1t, W2t, b1p, b2p, accum);
    conv_a_bf16<<<6144, 256, 0, stream>>>(in_x, Abf);
    conv1_gemm<<<dim3(3, 512), 256, 0, stream>>>(Abf, W1t, x, b1p, accum);
    gather_all<<<2944, 256, 0, stream>>>(x, accum, bns, bnb, q0, q1, q2, vt0, vt1, vt2);
    qq_all<<<996, 256, 0, stream>>>(q0, q1, q2, S0, pG1, pG2);
    softmax_all<<<5632, 256, 0, stream>>>(S0, pG1, pG2, S1, S2, atnb0, atnb1, atnb2, Ysp);
    pv_all<<<992, 256, 0, stream>>>(atnb0, atnb1, atnb2, vt0, vt1, vt2, Ysp, pP0, pP1, cnt);
    gemm_f32<<<dim3(2, 512), 256, 0, stream>>>(Ysp, W2t, out, b2p, 192, 180, 180);
}

// Round 12
// 408.761 us; speedup vs baseline: 1.3722x; 1.3722x over previous
//
#include <hip/hip_runtime.h>

typedef unsigned short u16;
typedef __bf16 bf16x8 __attribute__((ext_vector_type(8)));
typedef float f32x4 __attribute__((ext_vector_type(4)));
typedef u16 u16x4 __attribute__((ext_vector_type(4)));
typedef u16 u16x8 __attribute__((ext_vector_type(8)));

__device__ __forceinline__ u16 f2bf(float v) {
    unsigned u = __float_as_uint(v);
    unsigned r = (u + 0x7fffu + ((u >> 16) & 1u)) >> 16;
    return (u16)r;
}
__device__ __forceinline__ float bf2f(u16 u) { return __uint_as_float(((unsigned)u) << 16); }

__device__ __forceinline__ void async_cp16(const u16* g, u16* l) {
    __builtin_amdgcn_global_load_lds((const __attribute__((address_space(1))) unsigned int*)g,
                                     (__attribute__((address_space(3))) unsigned int*)l, 16, 0, 0);
}

// bijective XCD-chunked swizzle (m204 variant)
__device__ __forceinline__ int xcd_swz(int local, int n) {
    const int q = n >> 3, r = n & 7;
    const int xcd = local & 7, j = local >> 3;
    const int base = xcd < r ? xcd * (q + 1) : r * (q + 1) + (xcd - r) * q;
    return base + j;
}

// LDS anti-bank-conflict swizzle (T2, rule #21): 16B k-group g within a 64B row r is
// stored at slot g ^ ((r>>1)&3); permutation applied on the GLOBAL source (staging)
// and on the read offset (gload_lds dest must stay linear).
#define LKSWZ(tid) ((((tid) & 3) ^ (((tid) >> 3) & 3)) << 3)
#define ROSWZ(lane) (((lane) & 15) * 32 + ((((lane) >> 4) ^ (((lane) >> 1) & 3)) << 3))

// ---------------- fused prep + A fp32->bf16 convert ----------------
// blocks [0,6144): convert 65536x180 f32 -> 65536x192 bf16 (pad 0), 8 cols/thread.
// blocks [6144,6785): prep (W1t/W2t transpose+cast, padded biases, accum zero).
__global__ __launch_bounds__(256) void prep_convert(
    const float* __restrict__ A, u16* __restrict__ Abf,
    const float* __restrict__ W1, const float* __restrict__ W2,
    const float* __restrict__ b1, const float* __restrict__ b2,
    u16* __restrict__ W1t, u16* __restrict__ W2t,
    float* __restrict__ b1p, float* __restrict__ b2p, float* __restrict__ accum)
{
    if (blockIdx.x < 6144) {
        const long idx = (long)blockIdx.x * 256 + threadIdx.x;
        const long row = idx / 24;
        const int q = (int)(idx - row * 24);
        u16x8 o = {0, 0, 0, 0, 0, 0, 0, 0};
        if (q < 22) {
            const f32x4 v0 = *(const f32x4*)(A + row * 180L + q * 8);
            const f32x4 v1 = *(const f32x4*)(A + row * 180L + q * 8 + 4);
#pragma unroll
            for (int c = 0; c < 4; c++) { o[c] = f2bf(v0[c]); o[4 + c] = f2bf(v1[c]); }
        } else if (q == 22) {   // cols 176..183: 4 valid + 4 pad
            const f32x4 v0 = *(const f32x4*)(A + row * 180L + 176);
#pragma unroll
            for (int c = 0; c < 4; c++) o[c] = f2bf(v0[c]);
        }
        *(u16x8*)(Abf + row * 192L + q * 8) = o;
        return;
    }
    const int bid = blockIdx.x - 6144;
    const int t = threadIdx.x;
    if (t >= 192) return;
    if (bid < 384) {
        W1t[bid * 192 + t] = (bid < 360 && t < 180) ? f2bf(W1[t * 360 + bid]) : (u16)0;
    } else if (bid < 640) {
        const int n = bid - 384;
        W2t[n * 192 + t] = (n < 180 && t < 180) ? f2bf(W2[t * 180 + n]) : (u16)0;
    } else {
#pragma unroll
        for (int j = 0; j < 4; j++) {
            const int i = t + 192 * j;
            if (i < 384) b1p[i] = (i < 360) ? b1[i] : 0.0f;
            else if (i < 640) { const int k = i - 384; b2p[k] = (k < 180) ? b2[k] : 0.0f; }
            if (i < 768) accum[i] = 0.0f;
        }
    }
}

// ---------------- conv2 GEMM (fp32 out, bias, col guard) ----------------
__global__ __launch_bounds__(256) void gemm_f32(
    const u16* __restrict__ A, const u16* __restrict__ B,
    float* __restrict__ C, const float* __restrict__ bias,
    int K, int ldc, int n_store)
{
    __shared__ char smem[32768];
    u16* As = (u16*)smem;
    u16* Bs = (u16*)(smem + 8192);
    const int tid = threadIdx.x;
    const int lane = tid & 63;
    const int wave = tid >> 6;
    const int wm = wave >> 1, wn = wave & 1;
    const long m0 = (long)blockIdx.y * 128;
    const long n0 = (long)blockIdx.x * 128;

    f32x4 acc[4][4] = {};
    const int lrow = tid >> 2;
    const int lk = LKSWZ(tid);
    const u16* Ag = A + (m0 + lrow) * (long)K + lk;
    const u16* Bg = B + (n0 + lrow) * (long)K + lk;
    u16* Asl = As + tid * 8;
    u16* Bsl = Bs + tid * 8;
    const long K64 = (long)64 * K;
    const int ro = ROSWZ(lane);
    const int nsteps = K >> 5;

    async_cp16(Ag, Asl);
    async_cp16(Ag + K64, Asl + 2048);
    async_cp16(Bg, Bsl);
    async_cp16(Bg + K64, Bsl + 2048);
    __syncthreads();

    int cur = 0;
    for (int s = 0; s < nsteps; s++) {
        if (s + 1 < nsteps) {
            const int kn = (s + 1) << 5;
            u16* An = Asl + ((cur ^ 1) << 13);
            u16* Bn = Bsl + ((cur ^ 1) << 13);
            async_cp16(Ag + kn, An);
            async_cp16(Ag + kn + K64, An + 2048);
            async_cp16(Bg + kn, Bn);
            async_cp16(Bg + kn + K64, Bn + 2048);
        }
        bf16x8 af[4], bg[4];
        const u16* Asc = As + (cur << 13);
        const u16* Bsc = Bs + (cur << 13);
#pragma unroll
        for (int i = 0; i < 4; i++) af[i] = *(const bf16x8*)(Asc + (wm * 64 + i * 16) * 32 + ro);
#pragma unroll
        for (int j = 0; j < 4; j++) bg[j] = *(const bf16x8*)(Bsc + (wn * 64 + j * 16) * 32 + ro);
#pragma unroll
        for (int i = 0; i < 4; i++)
#pragma unroll
            for (int j = 0; j < 4; j++)
                acc[i][j] = __builtin_amdgcn_mfma_f32_16x16x32_bf16(af[i], bg[j], acc[i][j], 0, 0, 0);
        __syncthreads();
        cur ^= 1;
    }

    float bv[4];
#pragma unroll
    for (int j = 0; j < 4; j++) bv[j] = bias[n0 + wn * 64 + j * 16 + (lane & 15)];

    float* Cs = (float*)smem;
    for (int c = 0; c < 4; c++) {
        __syncthreads();
        if (wm == (c >> 1)) {
#pragma unroll
            for (int ii = 0; ii < 2; ii++) {
                const int i = (c & 1) * 2 + ii;
#pragma unroll
                for (int j = 0; j < 4; j++)
#pragma unroll
                    for (int r = 0; r < 4; r++) {
                        const int lr = ii * 16 + ((lane >> 4) << 2) + r;
                        Cs[lr * 128 + wn * 64 + j * 16 + (lane & 15)] = acc[i][j][r] + bv[j];
                    }
            }
        }
        __syncthreads();
        const int lr = tid >> 3;
        const int cg = (tid & 7) * 16;
        const long rowg = m0 + c * 32 + lr;
#pragma unroll
        for (int e = 0; e < 4; e++) {
            const int colg = cg + e * 4;
            if ((int)n0 + colg < n_store)
                *(f32x4*)(C + rowg * (long)ldc + n0 + colg) = *(const f32x4*)(Cs + lr * 128 + colg);
        }
    }
}

// ---------------- conv1: x = Abf(65536x192 bf16) @ W1t^T + b1, dbuf gload_lds, fused BN stats ----------------
__global__ __launch_bounds__(256) void conv1_gemm(
    const u16* __restrict__ A, const u16* __restrict__ B,
    u16* __restrict__ C, const float* __restrict__ bias, float* __restrict__ accum)
{
    __shared__ char smem[32768];
    u16* As = (u16*)smem;
    u16* Bs = (u16*)(smem + 8192);
    const int tid = threadIdx.x;
    const int lane = tid & 63;
    const int wave = tid >> 6;
    const int wm = wave >> 1, wn = wave & 1;
    const long m0 = (long)blockIdx.y * 128;
    const long n0 = (long)blockIdx.x * 128;

    f32x4 acc[4][4] = {};
    const int lrow = tid >> 2;
    const int lk = LKSWZ(tid);
    const u16* Ag = A + (m0 + lrow) * 192L + lk;
    const u16* Bg = B + (n0 + lrow) * 192L + lk;
    u16* Asl = As + tid * 8;
    u16* Bsl = Bs + tid * 8;
    const long K64 = 64L * 192;
    const int ro = ROSWZ(lane);
    const int nsteps = 6;

    async_cp16(Ag, Asl);
    async_cp16(Ag + K64, Asl + 2048);
    async_cp16(Bg, Bsl);
    async_cp16(Bg + K64, Bsl + 2048);
    __syncthreads();

    int cur = 0;
    for (int s = 0; s < nsteps; s++) {
        if (s + 1 < nsteps) {
            const int kn = (s + 1) << 5;
            u16* An = Asl + ((cur ^ 1) << 13);
            u16* Bn = Bsl + ((cur ^ 1) << 13);
            async_cp16(Ag + kn, An);
            async_cp16(Ag + kn + K64, An + 2048);
            async_cp16(Bg + kn, Bn);
            async_cp16(Bg + kn + K64, Bn + 2048);
        }
        bf16x8 af[4], bg[4];
        const u16* Asc = As + (cur << 13);
        const u16* Bsc = Bs + (cur << 13);
#pragma unroll
        for (int i = 0; i < 4; i++) af[i] = *(const bf16x8*)(Asc + (wm * 64 + i * 16) * 32 + ro);
#pragma unroll
        for (int j = 0; j < 4; j++) bg[j] = *(const bf16x8*)(Bsc + (wn * 64 + j * 16) * 32 + ro);
#pragma unroll
        for (int i = 0; i < 4; i++)
#pragma unroll
            for (int j = 0; j < 4; j++)
                acc[i][j] = __builtin_amdgcn_mfma_f32_16x16x32_bf16(af[i], bg[j], acc[i][j], 0, 0, 0);
        __syncthreads();
        cur ^= 1;
    }

    float bv[4];
#pragma unroll
    for (int j = 0; j < 4; j++) bv[j] = bias[n0 + wn * 64 + j * 16 + (lane & 15)];

    // fused BN stats: sum ROUNDED bf16 values (matches what consumers read).
    {
        float bs[4], bs2[4];
#pragma unroll
        for (int j = 0; j < 4; j++) {
            float s = 0.0f, s2 = 0.0f;
#pragma unroll
            for (int i = 0; i < 4; i++)
#pragma unroll
                for (int r = 0; r < 4; r++) {
                    const float v = bf2f(f2bf(acc[i][j][r] + bv[j]));
                    s += v; s2 += v * v;
                }
            s += __shfl_xor(s, 16, 64);  s += __shfl_xor(s, 32, 64);
            s2 += __shfl_xor(s2, 16, 64); s2 += __shfl_xor(s2, 32, 64);
            bs[j] = s; bs2[j] = s2;
        }
        if (lane < 16) {
#pragma unroll
            for (int j = 0; j < 4; j++) {
                const int ch = (int)n0 + wn * 64 + j * 16 + lane;
                atomicAdd(&accum[ch], bs[j]);
                atomicAdd(&accum[384 + ch], bs2[j]);
            }
        }
    }

    u16* Cs = (u16*)smem;
    for (int c = 0; c < 2; c++) {
        __syncthreads();
        if (wm == c) {
#pragma unroll
            for (int i = 0; i < 4; i++)
#pragma unroll
                for (int j = 0; j < 4; j++)
#pragma unroll
                    for (int r = 0; r < 4; r++) {
                        const int lr = i * 16 + ((lane >> 4) << 2) + r;
                        Cs[lr * 128 + wn * 64 + j * 16 + (lane & 15)] = f2bf(acc[i][j][r] + bv[j]);
                    }
        }
        __syncthreads();
        const int lr = tid >> 2;
        const int cg = (tid & 3) * 32;
        const long rowg = m0 + c * 64 + lr;
#pragma unroll
        for (int e = 0; e < 4; e++) {
            const int colg = cg + e * 8;
            *(u16x8*)(C + rowg * 384L + n0 + colg) = *(const u16x8*)(Cs + lr * 128 + colg);
        }
    }
}

// ---------------- grouped qq^T: SYMMETRIC (upper-tri) + split-K + XCD swizzle + dbuf ----------------
// blocks: [0,528) g0 tri(32) z=1 | [528,816) g1 tri(8) z=8 | [816,996) g2 tri(2) z=60
__global__ __launch_bounds__(256) void qq_all(
    const u16* __restrict__ q0, const u16* __restrict__ q1, const u16* __restrict__ q2,
    float* __restrict__ S0, float* __restrict__ pG1, float* __restrict__ pG2)
{
    __shared__ char smem[32768];
    u16* As = (u16*)smem;
    u16* Bs = (u16*)(smem + 8192);
    const int bid = blockIdx.x;
    int seg, local;
    if (bid < 528) { seg = 0; local = xcd_swz(bid, 528); }
    else if (bid < 816) { seg = 1; local = xcd_swz(bid - 528, 288); }
    else { seg = 2; local = xcd_swz(bid - 816, 180); }
    const int tX = seg == 0 ? 32 : (seg == 1 ? 8 : 2);
    const int TT = (tX * (tX + 1)) >> 1;
    const int K = seg == 0 ? 1024 : (seg == 1 ? 3840 : 15360);
    const int Ksplit = seg == 0 ? 1024 : (seg == 1 ? 480 : 256);
    const int N = seg == 0 ? 4096 : (seg == 1 ? 1024 : 256);
    const u16* A = seg == 0 ? q0 : (seg == 1 ? q1 : q2);
    float* outP = seg == 0 ? S0 : (seg == 1 ? pG1 : pG2);
    const int z = local / TT;
    int rem = local - z * TT;
    int by = 0, rowlen = tX;
    while (rem >= rowlen) { rem -= rowlen; by++; rowlen--; }
    const int bx = by + rem;

    const int tid = threadIdx.x;
    const int lane = tid & 63;
    const int wave = tid >> 6;
    const int wm = wave >> 1, wn = wave & 1;
    const long m0 = (long)by * 128;
    const long n0 = (long)bx * 128;
    const int kbeg = z * Ksplit;

    f32x4 acc[4][4] = {};
    const int lrow = tid >> 2;
    const int lk = LKSWZ(tid);
    const u16* Ag = A + (m0 + lrow) * (long)K + lk;
    const u16* Bg = A + (n0 + lrow) * (long)K + lk;
    u16* Asl = As + tid * 8;
    u16* Bsl = Bs + tid * 8;
    const long K64 = (long)64 * K;
    const int ro = ROSWZ(lane);
    const int nsteps = Ksplit >> 5;

    async_cp16(Ag + kbeg, Asl);
    async_cp16(Ag + kbeg + K64, Asl + 2048);
    async_cp16(Bg + kbeg, Bsl);
    async_cp16(Bg + kbeg + K64, Bsl + 2048);
    __syncthreads();

    int cur = 0;
    for (int s = 0; s < nsteps; s++) {
        if (s + 1 < nsteps) {
            const int kn = kbeg + ((s + 1) << 5);
            u16* An = Asl + ((cur ^ 1) << 13);
            u16* Bn = Bsl + ((cur ^ 1) << 13);
            async_cp16(Ag + kn, An);
            async_cp16(Ag + kn + K64, An + 2048);
            async_cp16(Bg + kn, Bn);
            async_cp16(Bg + kn + K64, Bn + 2048);
        }
        bf16x8 af[4], bg[4];
        const u16* Asc = As + (cur << 13);
        const u16* Bsc = Bs + (cur << 13);
#pragma unroll
        for (int i = 0; i < 4; i++) af[i] = *(const bf16x8*)(Asc + (wm * 64 + i * 16) * 32 + ro);
#pragma unroll
        for (int j = 0; j < 4; j++) bg[j] = *(const bf16x8*)(Bsc + (wn * 64 + j * 16) * 32 + ro);
#pragma unroll
        for (int i = 0; i < 4; i++)
#pragma unroll
            for (int j = 0; j < 4; j++)
                acc[i][j] = __builtin_amdgcn_mfma_f32_16x16x32_bf16(af[i], bg[j], acc[i][j], 0, 0, 0);
        __syncthreads();
        cur ^= 1;
    }

    float* Pz = outP + (long)z * N * N;

    // mirror write (transposed tile) straight from accumulators
    if (bx != by) {
        const int r0 = (int)n0 + wn * 64 + (lane & 15);
        const int c0 = (int)m0 + wm * 64 + ((lane >> 4) << 2);
#pragma unroll
        for (int j = 0; j < 4; j++) {
            float* rp = Pz + (long)(r0 + j * 16) * N + c0;
#pragma unroll
            for (int i = 0; i < 4; i++)
                *(f32x4*)(rp + i * 16) = acc[i][j];
        }
    }

    float* Cs = (float*)smem;
    for (int c = 0; c < 4; c++) {
        __syncthreads();
        if (wm == (c >> 1)) {
#pragma unroll
            for (int ii = 0; ii < 2; ii++) {
                const int i = (c & 1) * 2 + ii;
#pragma unroll
                for (int j = 0; j < 4; j++)
#pragma unroll
                    for (int r = 0; r < 4; r++) {
                        const int lr = ii * 16 + ((lane >> 4) << 2) + r;
                        Cs[lr * 128 + wn * 64 + j * 16 + (lane & 15)] = acc[i][j][r];
                    }
            }
        }
        __syncthreads();
        const int lr = tid >> 3;
        const int cg = (tid & 7) * 16;
        const long rowg = m0 + c * 32 + lr;
#pragma unroll
        for (int e = 0; e < 4; e++) {
            const int colg = cg + e * 4;
            *(f32x4*)(Pz + rowg * (long)N + n0 + colg) = *(const f32x4*)(Cs + lr * 128 + colg);
        }
    }
}

// ---------------- grouped PV (XCD swizzle + dbuf) ----------------
// blocks: [0,512) g0 8x32 split-K z=2 (fp32 partials) | [512,752) g1 30x8 | [752,992) g2 120x2
__global__ __launch_bounds__(256, 4) void pv_all(
    const u16* __restrict__ a0, const u16* __restrict__ a1, const u16* __restrict__ a2,
    const u16* __restrict__ vt0, const u16* __restrict__ vt1, const u16* __restrict__ vt2,
    u16* __restrict__ Ysp, float* __restrict__ pP0, float* __restrict__ pP1)
{
    __shared__ char smem[32768];
    u16* As = (u16*)smem;
    u16* Bs = (u16*)(smem + 8192);
    const int bid = blockIdx.x;
    int seg, local, z = 0;
    if (bid < 512) { seg = 0; const int l = xcd_swz(bid, 512); z = l >> 8; local = l & 255; }
    else if (bid < 752) { seg = 1; local = xcd_swz(bid - 512, 240); }
    else { seg = 2; local = xcd_swz(bid - 752, 240); }
    const int tX = seg == 0 ? 8 : (seg == 1 ? 30 : 120);
    const int K = seg == 0 ? 4096 : (seg == 1 ? 1024 : 256);
    const int Ksplit = seg == 0 ? 2048 : K;
    const int D = seg == 0 ? 960 : (seg == 1 ? 3840 : 15360);
    const int l2ws = 2 + seg;
    const int l2wc = 5 - seg;
    const u16* A = seg == 0 ? a0 : (seg == 1 ? a1 : a2);
    const u16* B = seg == 0 ? vt0 : (seg == 1 ? vt1 : vt2);
    const int bx = local % tX;
    const int by = local / tX;

    const int tid = threadIdx.x;
    const int lane = tid & 63;
    const int wave = tid >> 6;
    const int wm = wave >> 1, wn = wave & 1;
    const long m0 = (long)by * 128;     // n (window) rows
    const long n0 = (long)bx * 128;     // d cols
    const int kbeg = z * Ksplit;

    f32x4 acc[4][4] = {};
    const int lrow = tid >> 2;
    const int lk = LKSWZ(tid);
    const u16* Ag = A + (m0 + lrow) * (long)K + lk;
    const u16* Bg = B + (n0 + lrow) * (long)K + lk;
    u16* Asl = As + tid * 8;
    u16* Bsl = Bs + tid * 8;
    const long K64 = (long)64 * K;
    const int ro = ROSWZ(lane);
    const int nsteps = Ksplit >> 5;

    async_cp16(Ag + kbeg, Asl);
    async_cp16(Ag + kbeg + K64, Asl + 2048);
    async_cp16(Bg + kbeg, Bsl);
    async_cp16(Bg + kbeg + K64, Bsl + 2048);
    __syncthreads();

    int cur = 0;
    for (int s = 0; s < nsteps; s++) {
        if (s + 1 < nsteps) {
            const int kn = kbeg + ((s + 1) << 5);
            u16* An = Asl + ((cur ^ 1) << 13);
            u16* Bn = Bsl + ((cur ^ 1) << 13);
            async_cp16(Ag + kn, An);
            async_cp16(Ag + kn + K64, An + 2048);
            async_cp16(Bg + kn, Bn);
            async_cp16(Bg + kn + K64, Bn + 2048);
        }
        bf16x8 af[4], bg[4];
        const u16* Asc = As + (cur << 13);
        const u16* Bsc = Bs + (cur << 13);
#pragma unroll
        for (int i = 0; i < 4; i++) af[i] = *(const bf16x8*)(Asc + (wm * 64 + i * 16) * 32 + ro);
#pragma unroll
        for (int j = 0; j < 4; j++) bg[j] = *(const bf16x8*)(Bsc + (wn * 64 + j * 16) * 32 + ro);
#pragma unroll
        for (int i = 0; i < 4; i++)
#pragma unroll
            for (int j = 0; j < 4; j++)
                acc[i][j] = __builtin_amdgcn_mfma_f32_16x16x32_bf16(af[i], bg[j], acc[i][j], 0, 0, 0);
        __syncthreads();
        cur ^= 1;
    }

    if (seg == 0) {
        // fp32 partial write (4096 x 1024 row-major), coalesced via LDS restage
        float* Pz = (z == 0) ? pP0 : pP1;
        float* Cs = (float*)smem;
        for (int c = 0; c < 4; c++) {
            __syncthreads();
            if (wm == (c >> 1)) {
#pragma unroll
                for (int ii = 0; ii < 2; ii++) {
                    const int i = (c & 1) * 2 + ii;
#pragma unroll
                    for (int j = 0; j < 4; j++)
#pragma unroll
                        for (int r = 0; r < 4; r++) {
                            const int lr = ii * 16 + ((lane >> 4) << 2) + r;
                            Cs[lr * 128 + wn * 64 + j * 16 + (lane & 15)] = acc[i][j][r];
                        }
                }
            }
            __syncthreads();
            const int lr = tid >> 3;
            const int cg = (tid & 7) * 16;
            const long rowg = m0 + c * 32 + lr;
#pragma unroll
            for (int e = 0; e < 4; e++) {
                const int colg = cg + e * 4;
                *(f32x4*)(Pz + rowg * 1024L + n0 + colg) = *(const f32x4*)(Cs + lr * 128 + colg);
            }
        }
        return;
    }

    // g1/g2: bf16 scatter epilogue
    u16* Cs = (u16*)smem;
    const int wcm = (1 << l2wc) - 1;
    const int wsm = (1 << l2ws) - 1;
    const int sh = 1 << (l2ws - 1);
    for (int c = 0; c < 2; c++) {
        __syncthreads();
        if (wm == c) {
#pragma unroll
            for (int i = 0; i < 4; i++)
#pragma unroll
                for (int j = 0; j < 4; j++)
#pragma unroll
                    for (int r = 0; r < 4; r++) {
                        const int lr = i * 16 + ((lane >> 4) << 2) + r;
                        Cs[lr * 128 + wn * 64 + j * 16 + (lane & 15)] = f2bf(acc[i][j][r]);
                    }
        }
        __syncthreads();
        const int lr = tid >> 2;
        const int cgbase = (tid & 3) * 32;
        const int n = (int)m0 + c * 64 + lr;
        const int wi = n & wcm;
        const int hi = (n >> l2wc) & wcm;
        const int bb = n >> (2 * l2wc);
        const int rowb = (hi << l2ws) + sh;
        const int colb = (wi << l2ws) + sh;
        const long bbase = (long)bb * 128 * 128 * 192 + 60 * seg;
#pragma unroll
        for (int e = 0; e < 8; e++) {
            const int colg = cgbase + e * 4;
            const int d = (int)n0 + colg;
            if (d < D) {
                const int cc = d % 60;
                const int pp = d / 60;
                const int dh = pp >> l2ws;
                const int dw = pp & wsm;
                const int row = (rowb + dh) & 127;
                const int col = (colb + dw) & 127;
                *(u16x4*)(Ysp + bbase + ((long)row * 128 + col) * 192 + cc) =
                    *(const u16x4*)(Cs + lr * 128 + colg);
            }
        }
    }
}

// ---------------- g0 split-K reduce + windowed scatter into Ysp ----------------
__global__ __launch_bounds__(256) void reduce_scatter_g0(
    const float* __restrict__ pP0, const float* __restrict__ pP1, u16* __restrict__ Ysp)
{
    const int n = blockIdx.x;
    const int d = threadIdx.x * 4;
    if (d >= 960) return;
    const long i = (long)n * 1024 + d;
    f32x4 s = *(const f32x4*)(pP0 + i) + *(const f32x4*)(pP1 + i);
    const int cc = d % 60;
    const int pp = d / 60;
    const int dh = pp >> 2;
    const int dw = pp & 3;
    const int wi = n & 31;
    const int hi = (n >> 5) & 31;
    const int b = n >> 10;
    const int row = ((hi << 2) + dh + 2) & 127;
    const int col = ((wi << 2) + dw + 2) & 127;
    u16x4 o;
#pragma unroll
    for (int c = 0; c < 4; c++) o[c] = f2bf(s[c]);
    *(u16x4*)(Ysp + ((long)((b << 7) + row) * 128 + col) * 192 + cc) = o;
}

// ---------------- grouped gather + inline BN + transpose ----------------
// blocks: [0,1024) g0 16x64 | [1024,1984) g1 60x16 | [1984,2944) g2 240x4
__global__ __launch_bounds__(256) void gather_all(
    const u16* __restrict__ x, const float* __restrict__ accum,
    const float* __restrict__ bns, const float* __restrict__ bnb,
    u16* __restrict__ q0, u16* __restrict__ q1, u16* __restrict__ q2,
    u16* __restrict__ vt0, u16* __restrict__ vt1, u16* __restrict__ vt2)
{
    __shared__ u16 t[64][65];
    const int bid = blockIdx.x;
    int seg, local;
    if (bid < 1024) { seg = 0; local = bid; }
    else if (bid < 1984) { seg = 1; local = bid - 1024; }
    else { seg = 2; local = bid - 1984; }
    const int tX = seg == 0 ? 16 : (seg == 1 ? 60 : 240);
    const int N = seg == 0 ? 4096 : (seg == 1 ? 1024 : 256);
    const int D = seg == 0 ? 960 : (seg == 1 ? 3840 : 15360);
    const int Dp = seg == 0 ? 1024 : (seg == 1 ? 3840 : 15360);
    const int l2ws = 2 + seg;
    const int l2wc = 5 - seg;
    u16* q = seg == 0 ? q0 : (seg == 1 ? q1 : q2);
    u16* vt = seg == 0 ? vt0 : (seg == 1 ? vt1 : vt2);
    const int bx = local % tX;
    const int by = local / tX;

    const int d0 = bx * 64;
    const int n0 = by * 64;
    const int tc = threadIdx.x & 63;
    const int tr = threadIdx.x >> 6;

    const int d = d0 + tc;
    const int sh = 1 << (l2ws - 1);
    const int cc = d % 60;
    const int pp = d / 60;
    const int dh = pp >> l2ws;
    const int dw = pp & ((1 << l2ws) - 1);
    const int wcm = (1 << l2wc) - 1;
    const int ch = 120 * seg + cc;
    // inline bn_finalize
    const float m_q = accum[ch] * (1.0f / 65536.0f);
    const float v_q = accum[384 + ch] * (1.0f / 65536.0f) - m_q * m_q;
    const float seq = bns[ch] * rsqrtf(v_q + 1e-5f);
    const float beq = bnb[ch] - m_q * seq;
    const float m_v = accum[ch + 60] * (1.0f / 65536.0f);
    const float v_v = accum[384 + ch + 60] * (1.0f / 65536.0f) - m_v * m_v;
    const float sev = bns[ch + 60] * rsqrtf(v_v + 1e-5f);
    const float bev = bnb[ch + 60] - m_v * sev;
    const bool valid = d < D;

#pragma unroll 4
    for (int i = 0; i < 16; i++) {
        const int n = n0 + i * 4 + tr;
        const int wi = n & wcm;
        const int hi = (n >> l2wc) & wcm;
        const int b = n >> (2 * l2wc);
        const int row = ((hi << l2ws) + dh + sh) & 127;
        const int col = ((wi << l2ws) + dw + sh) & 127;
        const long src = ((long)((b << 7) + row) * 128 + col) * 384 + ch;
        const float xq = bf2f(x[src]);
        const float xv = bf2f(x[src + 60]);
        q[(long)n * Dp + d] = valid ? f2bf(seq * xq + beq) : (u16)0;
        t[tc][i * 4 + tr] = f2bf(sev * xv + bev);
    }
    __syncthreads();
#pragma unroll 4
    for (int i = 0; i < 16; i++) {
        const int dd = i * 4 + tr;
        vt[(long)(d0 + dd) * N + n0 + tc] = t[dd][tc];
    }
}

// ---------------- grouped softmax (fused split-K reduce) + zero_pad merged ----------------
template <int VPT>
__device__ __forceinline__ void softmax_body(
    const float* __restrict__ P, int nsplit, long MN, int rowi,
    float* __restrict__ S, u16* __restrict__ Sb)
{
    const int N = VPT * 256;
    const long base = (long)rowi * N;
    float v[VPT];
    float mx = -3.0e38f;
#pragma unroll
    for (int i = 0; i < VPT; i++) {
        const long idx = base + i * 256 + threadIdx.x;
        float val = P[idx];
        for (int z = 1; z < nsplit; z++) val += P[(long)z * MN + idx];
        v[i] = val; mx = fmaxf(mx, val);
    }
#pragma unroll
    for (int o = 32; o > 0; o >>= 1) mx = fmaxf(mx, __shfl_down(mx, o, 64));
    __shared__ float redm[4];
    if ((threadIdx.x & 63) == 0) redm[threadIdx.x >> 6] = mx;
    __syncthreads();
    mx = fmaxf(fmaxf(redm[0], redm[1]), fmaxf(redm[2], redm[3]));
    float s = 0.0f;
#pragma unroll
    for (int i = 0; i < VPT; i++) { v[i] = __expf(v[i] - mx); s += v[i]; }
#pragma unroll
    for (int o = 32; o > 0; o >>= 1) s += __shfl_down(s, o, 64);
    __shared__ float reds[4];
    if ((threadIdx.x & 63) == 0) reds[threadIdx.x >> 6] = s;
    __syncthreads();
    s = reds[0] + reds[1] + reds[2] + reds[3];
    const float inv = 1.0f / s;
#pragma unroll
    for (int i = 0; i < VPT; i++) {
        const float r = v[i] * inv;
        const long idx = base + i * 256 + threadIdx.x;
        S[idx] = r;
        Sb[idx] = f2bf(r);
    }
}

__global__ __launch_bounds__(256) void softmax_all(
    float* __restrict__ S0, const float* __restrict__ pG1, const float* __restrict__ pG2,
    float* __restrict__ out1, float* __restrict__ out2,
    u16* __restrict__ ab0, u16* __restrict__ ab1, u16* __restrict__ ab2,
    u16* __restrict__ Ysp)
{
    const int r = blockIdx.x;
    if (r >= 5376) {   // zero Ysp pad cols 180..191 (merged zero_pad)
        const long rr = (long)(r - 5376) * 256 + threadIdx.x;
        u16* p = Ysp + rr * 192 + 180;
        const u16x4 zz = {0, 0, 0, 0};
        *(u16x4*)(p) = zz;
        *(u16x4*)(p + 4) = zz;
        *(u16x4*)(p + 8) = zz;
        return;
    }
    if (r < 4096)      softmax_body<16>(S0, 1, 16777216L, r, S0, ab0);
    else if (r < 5120) softmax_body<4>(pG1, 8, 1048576L, r - 4096, out1, ab1);
    else               softmax_body<1>(pG2, 60, 65536L, r - 5120, out2, ab2);
}

extern "C" void kernel_launch(void* const* d_in, const int* in_sizes, int n_in,
                              void* d_out, int out_size, void* d_ws, size_t ws_size,
                              hipStream_t stream)
{
    const float* in_x = (const float*)d_in[0];
    const float* w1  = (const float*)d_in[1];
    const float* b1  = (const float*)d_in[2];
    const float* bns = (const float*)d_in[3];
    const float* bnb = (const float*)d_in[4];
    const float* w2  = (const float*)d_in[5];
    const float* b2  = (const float*)d_in[6];
    float* out = (float*)d_out;

    char* w = (char*)d_ws;
    // region0 (33.55 MB): atnb0 (g0 bf16 atn, softmax_all -> pv_all)
    u16* atnb0 = (u16*)w;
    size_t off = 33554432;
    // x region (50.33 MB): x (conv1 out, dead after gather_all);
    //   then qq partials pG1 (33.55 @ +0), pG2 (15.73 @ +33.55) [dead after softmax_all];
    //   then Ysp (25.17 @ +0) and pP1 (g0 PV partial z1, 16.78 @ +25.17).
    u16* x = (u16*)(w + off);
    float* pG1 = (float*)(w + off);
    float* pG2 = (float*)(w + off + 33554432);
    u16* Ysp = (u16*)(w + off);
    float* pP1 = (float*)(w + off + 25165824);
    off += 50331648;
    u16* W1t = (u16*)(w + off);  off += 147456;
    u16* W2t = (u16*)(w + off);  off += 98304;
    float* b1p = (float*)(w + off);   off += 4096;
    float* b2p = (float*)(w + off);   off += 4096;
    float* accum = (float*)(w + off); off += 4096;
    u16* q0 = (u16*)(w + off);  off += 8388608;
    u16* q1 = (u16*)(w + off);  off += 7864320;
    u16* q2 = (u16*)(w + off);  off += 7864320;
    u16* vt0 = (u16*)(w + off); off += 8388608;
    u16* vt1 = (u16*)(w + off); off += 7864320;
    u16* vt2 = (u16*)(w + off); off += 7864320;
    u16* atnb1 = (u16*)(w + off); off += 2097152;
    u16* atnb2 = (u16*)(w + off); off += 131072;
    // pP0 (g0 PV partial z0, 16.78 MB) overlays dead q0/q1/q2 (24.1 MB)
    float* pP0 = (float*)q0;
    // Abf (65536x192 bf16, 25.17 MB) overlays q0..q2+head of vt0; dead before gather_all
    u16* Abf = q0;

    float* S0 = out + 11796480L;   // atn g0 (4096^2)
    float* S1 = out + 28573696L;   // atn g1 (1024^2)
    float* S2 = out + 29622272L;   // atn g2 (256^2)

    prep_convert<<<6785, 256, 0, stream>>>(in_x, Abf, w1, w2, b1, b2, W1t, W2t, b1p, b2p, accum);
    conv1_gemm<<<dim3(3, 512), 256, 0, stream>>>(Abf, W1t, x, b1p, accum);
    gather_all<<<2944, 256, 0, stream>>>(x, accum, bns, bnb, q0, q1, q2, vt0, vt1, vt2);
    qq_all<<<996, 256, 0, stream>>>(q0, q1, q2, S0, pG1, pG2);
    softmax_all<<<5632, 256, 0, stream>>>(S0, pG1, pG2, S1, S2, atnb0, atnb1, atnb2, Ysp);
    pv_all<<<992, 256, 0, stream>>>(atnb0, atnb1, atnb2, vt0, vt1, vt2, Ysp, pP0, pP1);
    reduce_scatter_g0<<<4096, 256, 0, stream>>>(pP0, pP1, Ysp);
    gemm_f32<<<dim3(2, 512), 256, 0, stream>>>(Ysp, W2t, out, b2p, 192, 180, 180);
}